// Round 10
// baseline (86.243 us; speedup 1.0000x reference)
//
#include <hip/hip_runtime.h>
#include <hip/hip_bf16.h>

// MultiHeadAttention (additive/Bahdanau): B=2, Q=K=256, HIDDEN=1024, 8 heads x 128
// Pipeline (3 kernels):
//  1) prep:      split query/keys -> bf16 hi/lo; W^T*2log2e -> bf16 hi/lo (LDS transpose)
//  2) gemm_mfma: 3-term bf16 MFMA GEMMs; epilogue FACTORS each output a into
//                m = 2^frac(a) in [1,2), i = floor(a), packed u32 = mant16<<16 | (i+32768).
//                Planes: PQ[512][1024], PKT[1024][512] (transposed free).
//  3) attn_fused: logits via t = ldexp(mq*mk, iq+ik); r = rcp(1+t)  [1 trans/elem, was 2]
//                 tanh(x) = 1 - 2r;  Va.tanh = ssum - 2*sum(va*r). Softmax + PV fused.
// R5-R8 evidence: attn pinned at 54us across occupancy/reuse variants -> trans-pipe-bound
// (beta ~ 25cyc/trans wave-inst). This round halves trans count.
// Requires ws_size >= 16 MB (verified in earlier rounds).

#define TANH_SCALE 2.88539008177792681472f   // 2*log2(e)
#define LOG2E      1.44269504088896340736f

typedef __attribute__((ext_vector_type(8))) short bf16x8_t;   // 8 bf16 = 4 VGPRs
typedef __attribute__((ext_vector_type(4))) float f32x4_t;

__device__ inline ushort bf16_rne(float f) {
  unsigned u = __float_as_uint(f);
  u += 0x7FFFu + ((u >> 16) & 1u);
  return (ushort)(u >> 16);
}
__device__ inline float bf16_to_f(ushort h) { return __uint_as_float((unsigned)h << 16); }
__device__ inline void split1(float v, ushort& hi, ushort& lo) {
  hi = bf16_rne(v);
  lo = bf16_rne(v - bf16_to_f(hi));
}

// factor a -> (m = 2^frac(a) in [1,2), i = floor(a)); pack mant16 | (i+32768)
__device__ inline unsigned pack_exp(float a) {
  float fa = floorf(a);
  float m = __builtin_amdgcn_exp2f(a - fa);
  unsigned mb = __float_as_uint(m);
  unsigned mant = (mb >= 0x40000000u) ? 0xFFFFu : ((mb >> 7) & 0xFFFFu);  // guard m->2.0 rounding
  return (mant << 16) | (((unsigned)((int)fa + 32768)) & 0xFFFFu);
}

__device__ inline float ldexp_f(float x, int e) {
  float r;
  asm("v_ldexp_f32 %0, %1, %2" : "=v"(r) : "v"(x), "v"(e));
  return r;
}

// ---------------- Kernel 1: prep (unchanged) ----------------
__global__ __launch_bounds__(256) void prep(
    const float* __restrict__ query, const float* __restrict__ keys,
    const float* __restrict__ Wq, const float* __restrict__ Wk,
    ushort* __restrict__ qhi, ushort* __restrict__ qlo,
    ushort* __restrict__ khi, ushort* __restrict__ klo,
    ushort* __restrict__ wqthi, ushort* __restrict__ wqtlo,
    ushort* __restrict__ wkthi, ushort* __restrict__ wktlo)
{
  __shared__ float t[64][65];
  const int bid = blockIdx.x, tid = threadIdx.x;
  if (bid < 1024) {
    const int z = bid >> 9;
    const float* in = z ? keys : query;
    ushort* hi = z ? khi : qhi;
    ushort* lo = z ? klo : qlo;
    const size_t i = ((size_t)(bid & 511) * 256 + tid) * 4;
    float4 v = *(const float4*)(in + i);
    ushort h0, h1, h2, h3, l0, l1, l2, l3;
    split1(v.x, h0, l0); split1(v.y, h1, l1);
    split1(v.z, h2, l2); split1(v.w, h3, l3);
    *(ushort4*)(hi + i) = make_ushort4(h0, h1, h2, h3);
    *(ushort4*)(lo + i) = make_ushort4(l0, l1, l2, l3);
  } else {
    const int idx = bid - 1024;
    const int z = idx >> 8;
    const float* W = z ? Wk : Wq;
    ushort* thi = z ? wkthi : wqthi;
    ushort* tlo = z ? wktlo : wqtlo;
    const int n0 = (idx & 15) * 64, h0 = ((idx >> 4) & 15) * 64;
    const int r = tid >> 4, c = (tid & 15) * 4;
#pragma unroll
    for (int i = 0; i < 4; ++i) {
      const int rr = r + i * 16;
      float4 wv = *(const float4*)(W + (size_t)(h0 + rr) * 1024 + n0 + c);
      t[rr][c + 0] = wv.x; t[rr][c + 1] = wv.y;
      t[rr][c + 2] = wv.z; t[rr][c + 3] = wv.w;
    }
    __syncthreads();
#pragma unroll
    for (int i = 0; i < 4; ++i) {
      const int rr = r + i * 16;
      ushort h0v, h1v, h2v, h3v, l0v, l1v, l2v, l3v;
      split1(t[c + 0][rr] * TANH_SCALE, h0v, l0v);
      split1(t[c + 1][rr] * TANH_SCALE, h1v, l1v);
      split1(t[c + 2][rr] * TANH_SCALE, h2v, l2v);
      split1(t[c + 3][rr] * TANH_SCALE, h3v, l3v);
      *(ushort4*)(thi + (size_t)(n0 + rr) * 1024 + h0 + c) = make_ushort4(h0v, h1v, h2v, h3v);
      *(ushort4*)(tlo + (size_t)(n0 + rr) * 1024 + h0 + c) = make_ushort4(l0v, l1v, l2v, l3v);
    }
  }
}

// ---------------- Kernel 2: MFMA GEMM, 3-term bf16 split; packed-factored epilogue ----------------
__global__ __launch_bounds__(256) void gemm_mfma(
    const ushort* __restrict__ qhi, const ushort* __restrict__ qlo,
    const ushort* __restrict__ khi, const ushort* __restrict__ klo,
    const ushort* __restrict__ wqthi, const ushort* __restrict__ wqtlo,
    const ushort* __restrict__ wkthi, const ushort* __restrict__ wktlo,
    unsigned* __restrict__ PQ, unsigned* __restrict__ PKT)
{
  const int z = blockIdx.y;
  const int bid = blockIdx.x;
  int m0, n0, ldc;
  const ushort *Ah_g, *Al_g, *Bh_g, *Bl_g;
  unsigned* C;
  if (z == 0) {             // PQ[512][1024]
    m0 = (bid >> 4) * 64; n0 = (bid & 15) * 64; ldc = 1024;
    Ah_g = qhi; Al_g = qlo; Bh_g = wqthi; Bl_g = wqtlo; C = PQ;
  } else {                  // PKT[1024][512]
    m0 = (bid >> 3) * 64; n0 = (bid & 7) * 64; ldc = 512;
    Ah_g = wkthi; Al_g = wktlo; Bh_g = khi; Bl_g = klo; C = PKT;
  }

  __shared__ __align__(16) ushort Ah[64 * 40];
  __shared__ __align__(16) ushort Al[64 * 40];
  __shared__ __align__(16) ushort Bh[64 * 40];
  __shared__ __align__(16) ushort Bl[64 * 40];

  const int tid = threadIdx.x;
  const int srow = tid >> 2, skc = (tid & 3) * 8;
  const size_t gA = (size_t)(m0 + srow) * 1024 + skc;
  const size_t gB = (size_t)(n0 + srow) * 1024 + skc;
  const int soff = srow * 40 + skc;

  uint4 rah = *(const uint4*)(Ah_g + gA);
  uint4 ral = *(const uint4*)(Al_g + gA);
  uint4 rbh = *(const uint4*)(Bh_g + gB);
  uint4 rbl = *(const uint4*)(Bl_g + gB);

  const int w = __builtin_amdgcn_readfirstlane(tid >> 6);
  const int lane = tid & 63;
  const int wm = (w >> 1) * 32, wn = (w & 1) * 32;
  const int fr = lane & 15, kg = lane >> 4;
  const int aoff = (wm + fr) * 40 + kg * 8;
  const int boff = (wn + fr) * 40 + kg * 8;

  f32x4_t acc[2][2] = {};

  for (int kk = 0; kk < 1024; kk += 32) {
    __syncthreads();
    *(uint4*)(Ah + soff) = rah;
    *(uint4*)(Al + soff) = ral;
    *(uint4*)(Bh + soff) = rbh;
    *(uint4*)(Bl + soff) = rbl;
    __syncthreads();

    if (kk + 32 < 1024) {
      rah = *(const uint4*)(Ah_g + gA + kk + 32);
      ral = *(const uint4*)(Al_g + gA + kk + 32);
      rbh = *(const uint4*)(Bh_g + gB + kk + 32);
      rbl = *(const uint4*)(Bl_g + gB + kk + 32);
    }

    bf16x8_t ah0 = *(const bf16x8_t*)(Ah + aoff);
    bf16x8_t ah1 = *(const bf16x8_t*)(Ah + aoff + 16 * 40);
    bf16x8_t al0 = *(const bf16x8_t*)(Al + aoff);
    bf16x8_t al1 = *(const bf16x8_t*)(Al + aoff + 16 * 40);
    bf16x8_t bh0 = *(const bf16x8_t*)(Bh + boff);
    bf16x8_t bh1 = *(const bf16x8_t*)(Bh + boff + 16 * 40);
    bf16x8_t bl0 = *(const bf16x8_t*)(Bl + boff);
    bf16x8_t bl1 = *(const bf16x8_t*)(Bl + boff + 16 * 40);

    acc[0][0] = __builtin_amdgcn_mfma_f32_16x16x32_bf16(ah0, bh0, acc[0][0], 0, 0, 0);
    acc[0][1] = __builtin_amdgcn_mfma_f32_16x16x32_bf16(ah0, bh1, acc[0][1], 0, 0, 0);
    acc[1][0] = __builtin_amdgcn_mfma_f32_16x16x32_bf16(ah1, bh0, acc[1][0], 0, 0, 0);
    acc[1][1] = __builtin_amdgcn_mfma_f32_16x16x32_bf16(ah1, bh1, acc[1][1], 0, 0, 0);
    acc[0][0] = __builtin_amdgcn_mfma_f32_16x16x32_bf16(ah0, bl0, acc[0][0], 0, 0, 0);
    acc[0][1] = __builtin_amdgcn_mfma_f32_16x16x32_bf16(ah0, bl1, acc[0][1], 0, 0, 0);
    acc[1][0] = __builtin_amdgcn_mfma_f32_16x16x32_bf16(ah1, bl0, acc[1][0], 0, 0, 0);
    acc[1][1] = __builtin_amdgcn_mfma_f32_16x16x32_bf16(ah1, bl1, acc[1][1], 0, 0, 0);
    acc[0][0] = __builtin_amdgcn_mfma_f32_16x16x32_bf16(al0, bh0, acc[0][0], 0, 0, 0);
    acc[0][1] = __builtin_amdgcn_mfma_f32_16x16x32_bf16(al0, bh1, acc[0][1], 0, 0, 0);
    acc[1][0] = __builtin_amdgcn_mfma_f32_16x16x32_bf16(al1, bh0, acc[1][0], 0, 0, 0);
    acc[1][1] = __builtin_amdgcn_mfma_f32_16x16x32_bf16(al1, bh1, acc[1][1], 0, 0, 0);
  }

#pragma unroll
  for (int fm = 0; fm < 2; ++fm)
#pragma unroll
    for (int fn = 0; fn < 2; ++fn) {
      const int col = n0 + wn + fn * 16 + fr;
#pragma unroll
      for (int j = 0; j < 4; ++j) {
        const int row = m0 + wm + fm * 16 + kg * 4 + j;
        C[(size_t)row * ldc + col] = pack_exp(acc[fm][fn][j]);
      }
    }
}

// ---------------- Kernel 3: fused attn, factored-exponent inner loop ----------------
// grid 512: block = (b,h) = bid>>5, q-tile = (bid&31)*8. Wave w: k = w*64+lane.
// hk chunk (16 d) unpacked in regs, reused across 8 q. hq/Va wave-uniform (SALU/SGPR).
// Per element: u = mq*mk; n = iq+ik; t = ldexp(u,n); r = rcp(t+1); acc += va*r.  [5 VALU + 1 trans]
__global__ __launch_bounds__(256) void attn_fused(
    const unsigned* __restrict__ PQ, const unsigned* __restrict__ PKT,
    const float* __restrict__ Va, const int* __restrict__ mask,
    const float* __restrict__ values,
    float* __restrict__ weights, float* __restrict__ ctx)
{
  __shared__ float red_m[4][8];
  __shared__ float red_s[4][8];
  __shared__ __align__(16) float P_lds[8][256];

  const int tid = threadIdx.x;
  const int lane = tid & 63;
  const int w = __builtin_amdgcn_readfirstlane(tid >> 6);
  const int bid = blockIdx.x;
  const int bh = bid >> 5;
  const int b = bh & 1, h = bh >> 1;
  const int qt = (bid & 31) * 8;
  const int k = w * 64 + lane;

  const float pen = 99.0f * (1.0f - (float)mask[b * 256 + k]);

  float ssum = Va[h * 128 + lane] + Va[h * 128 + 64 + lane];
#pragma unroll
  for (int off = 32; off; off >>= 1) ssum += __shfl_xor(ssum, off, 64);

  const unsigned* pkp = PKT + (size_t)(h * 128) * 512 + b * 256 + k;   // + d*512 (per-lane)
  const unsigned* pqb = PQ + (size_t)(b * 256 + qt) * 1024 + h * 128;  // + q*1024 + d (uniform)
  const float* vap = Va + h * 128;                                     // uniform

  float acc[8] = {0.f, 0.f, 0.f, 0.f, 0.f, 0.f, 0.f, 0.f};

  float mkc[16]; int ikc[16]; unsigned pkn[16];
#pragma unroll
  for (int j = 0; j < 16; ++j) pkn[j] = pkp[(size_t)j * 512];
#pragma unroll
  for (int j = 0; j < 16; ++j) {
    mkc[j] = __uint_as_float(0x3F800000u | ((pkn[j] >> 16) << 7));
    ikc[j] = (int)(pkn[j] & 0xFFFFu) - 32768;
  }

  for (int ch = 0; ch < 8; ++ch) {
    const int d0 = ch * 16;
    if (ch < 7) {   // raw prefetch of next chunk (consumed after the 8-q pass)
#pragma unroll
      for (int j = 0; j < 16; ++j) pkn[j] = pkp[(size_t)(d0 + 16 + j) * 512];
    }
#pragma unroll
    for (int q = 0; q < 8; ++q) {
      const unsigned* pqq = pqb + (size_t)q * 1024 + d0;   // wave-uniform
#pragma unroll
      for (int dd = 0; dd < 16; dd += 4) {
        uint4 pq4 = *(const uint4*)(pqq + dd);
        float4 va4 = *(const float4*)(vap + d0 + dd);
#pragma unroll
        for (int e = 0; e < 4; ++e) {
          const unsigned pqv = (e == 0) ? pq4.x : (e == 1) ? pq4.y : (e == 2) ? pq4.z : pq4.w;
          const float vav = (e == 0) ? va4.x : (e == 1) ? va4.y : (e == 2) ? va4.z : va4.w;
          const float mq = __uint_as_float(0x3F800000u | ((pqv >> 16) << 7));
          const int iq = (int)(pqv & 0xFFFFu) - 32768;
          float u_ = mq * mkc[dd + e];
          int n_ = iq + ikc[dd + e];
          float t_ = ldexp_f(u_, n_);
          acc[q] += vav * __builtin_amdgcn_rcpf(t_ + 1.0f);
        }
      }
    }
    if (ch < 7) {
#pragma unroll
      for (int j = 0; j < 16; ++j) {
        mkc[j] = __uint_as_float(0x3F800000u | ((pkn[j] >> 16) << 7));
        ikc[j] = (int)(pkn[j] & 0xFFFFu) - 32768;
      }
    }
  }

  // logits
  float l[8], p[8];
#pragma unroll
  for (int q = 0; q < 8; ++q) l[q] = ssum - 2.0f * acc[q] - pen;

  // row max: wave-reduce then cross-wave via LDS
#pragma unroll
  for (int q = 0; q < 8; ++q) {
    float m = l[q];
#pragma unroll
    for (int off = 32; off; off >>= 1) m = fmaxf(m, __shfl_xor(m, off, 64));
    if (lane == 0) red_m[w][q] = m;
  }
  __syncthreads();
#pragma unroll
  for (int q = 0; q < 8; ++q) {
    float m = fmaxf(fmaxf(red_m[0][q], red_m[1][q]), fmaxf(red_m[2][q], red_m[3][q]));
    p[q] = __builtin_amdgcn_exp2f((l[q] - m) * LOG2E);
  }
#pragma unroll
  for (int q = 0; q < 8; ++q) {
    float s = p[q];
#pragma unroll
    for (int off = 32; off; off >>= 1) s += __shfl_xor(s, off, 64);
    if (lane == 0) red_s[w][q] = s;
  }
  __syncthreads();
#pragma unroll
  for (int q = 0; q < 8; ++q) {
    const float s = (red_s[0][q] + red_s[1][q]) + (red_s[2][q] + red_s[3][q]);
    const float pq = p[q] / s;
    weights[((size_t)((b * 8 + h) * 256) + qt + q) * 256 + k] = pq;
    P_lds[q][k] = pq;
  }
  __syncthreads();

  // PV: wave w -> q rows {2w, 2w+1}; lane: d4 = lane&31, ks = lane>>5 (k-half).
  const int d4 = lane & 31, ks = lane >> 5;
  const int q0 = w * 2, q1 = q0 + 1;
  const float* vb = values + (size_t)(b * 256 + ks * 128) * 1024 + h * 128 + d4 * 4;
  float4 A0 = make_float4(0, 0, 0, 0), A1 = make_float4(0, 0, 0, 0);
#pragma unroll 2
  for (int k4 = 0; k4 < 32; ++k4) {
    float4 p0v = *(const float4*)&P_lds[q0][ks * 128 + k4 * 4];
    float4 p1v = *(const float4*)&P_lds[q1][ks * 128 + k4 * 4];
#pragma unroll
    for (int j = 0; j < 4; ++j) {
      float4 v = *(const float4*)(vb + (size_t)(k4 * 4 + j) * 1024);
      const float pj0 = (j == 0) ? p0v.x : (j == 1) ? p0v.y : (j == 2) ? p0v.z : p0v.w;
      const float pj1 = (j == 0) ? p1v.x : (j == 1) ? p1v.y : (j == 2) ? p1v.z : p1v.w;
      A0.x += pj0 * v.x; A0.y += pj0 * v.y; A0.z += pj0 * v.z; A0.w += pj0 * v.w;
      A1.x += pj1 * v.x; A1.y += pj1 * v.y; A1.z += pj1 * v.z; A1.w += pj1 * v.w;
    }
  }
  A0.x += __shfl_xor(A0.x, 32, 64); A0.y += __shfl_xor(A0.y, 32, 64);
  A0.z += __shfl_xor(A0.z, 32, 64); A0.w += __shfl_xor(A0.w, 32, 64);
  A1.x += __shfl_xor(A1.x, 32, 64); A1.y += __shfl_xor(A1.y, 32, 64);
  A1.z += __shfl_xor(A1.z, 32, 64); A1.w += __shfl_xor(A1.w, 32, 64);
  if (lane < 32) {
    *(float4*)&ctx[(size_t)(b * 256 + qt + q0) * 1024 + h * 128 + d4 * 4] = A0;
    *(float4*)&ctx[(size_t)(b * 256 + qt + q1) * 1024 + h * 128 + d4 * 4] = A1;
  }
}

extern "C" void kernel_launch(void* const* d_in, const int* in_sizes, int n_in,
                              void* d_out, int out_size, void* d_ws, size_t ws_size,
                              hipStream_t stream) {
  const float* query  = (const float*)d_in[0];
  const float* keys   = (const float*)d_in[1];
  const float* values = (const float*)d_in[2];
  const int*   mask   = (const int*)d_in[3];
  const float* Wq     = (const float*)d_in[4];
  const float* Wk     = (const float*)d_in[5];
  const float* Va     = (const float*)d_in[6];

  float* ctx     = (float*)d_out;            // [2,256,1024]
  float* weights = ctx + 524288;             // [2,8,256,256]

  // ws layout (16 MB total): 12 MB bf16 splits + 4 MB packed planes
  ushort* qhi   = (ushort*)d_ws;             // 512K elems each (1 MB)
  ushort* qlo   = qhi + 524288;
  ushort* khi   = qlo + 524288;
  ushort* klo   = khi + 524288;
  ushort* wqthi = klo + 524288;              // 1M elems each (2 MB)
  ushort* wqtlo = wqthi + 1048576;
  ushort* wkthi = wqtlo + 1048576;
  ushort* wktlo = wkthi + 1048576;
  unsigned* PQ  = (unsigned*)(wktlo + 1048576); // [512][1024] packed (2 MB)
  unsigned* PKT = PQ + 524288;                  // [1024][512] packed (2 MB)

  prep<<<dim3(1536), 256, 0, stream>>>(query, keys, Wq, Wk,
                                       qhi, qlo, khi, klo,
                                       wqthi, wqtlo, wkthi, wktlo);
  gemm_mfma<<<dim3(128, 2), 256, 0, stream>>>(qhi, qlo, khi, klo,
                                              wqthi, wqtlo, wkthi, wktlo, PQ, PKT);
  attn_fused<<<dim3(512), 256, 0, stream>>>(PQ, PKT, Va, mask, values, weights, ctx);
}

// Round 11
// 83.109 us; speedup vs baseline: 1.0377x; 1.0377x over previous
//
#include <hip/hip_runtime.h>
#include <hip/hip_bf16.h>

// MultiHeadAttention (additive/Bahdanau): B=2, Q=K=256, HIDDEN=1024, 8 heads x 128
// Pipeline (3 kernels):
//  1) prep:      split query/keys -> bf16 hi/lo; W^T*2log2e -> bf16 hi/lo (LDS transpose)
//  2) gemm_mfma: 3-term bf16 MFMA GEMMs; epilogue factors a' = 2log2e*x into
//                m = 2^frac(a') in [1,2) (f32 plane) and i = floor(a') (i32 plane).
//                Planes: MQ/IQ [512][1024], MKT/IKT [1024][512] (transposed free).
//  3) attn_fused: per elem: t = ldexp(mq*mk, iq+ik) = e^{2x}; r = rcp(t+1);
//                 logit = ssum - 2*sum(va*r) - pen.  [5 VALU + 1 trans, zero unpack]
//                 Softmax + PV fused (R8 shell).
// Fitted cost model (R5-R9): t_us ~ 0.874*(4.25*nVALU + 24.5*nTRANS) -> predicts ~38us here.
// ws_size = 256 MiB (observed via harness poison fill) -> plain f32/i32 planes, no packing.

#define TANH_SCALE 2.88539008177792681472f   // 2*log2(e)
#define LOG2E      1.44269504088896340736f

typedef __attribute__((ext_vector_type(8))) short bf16x8_t;   // 8 bf16 = 4 VGPRs
typedef __attribute__((ext_vector_type(4))) float f32x4_t;

__device__ inline ushort bf16_rne(float f) {
  unsigned u = __float_as_uint(f);
  u += 0x7FFFu + ((u >> 16) & 1u);
  return (ushort)(u >> 16);
}
__device__ inline float bf16_to_f(ushort h) { return __uint_as_float((unsigned)h << 16); }
__device__ inline void split1(float v, ushort& hi, ushort& lo) {
  hi = bf16_rne(v);
  lo = bf16_rne(v - bf16_to_f(hi));
}

// ---------------- Kernel 1: prep (unchanged) ----------------
__global__ __launch_bounds__(256) void prep(
    const float* __restrict__ query, const float* __restrict__ keys,
    const float* __restrict__ Wq, const float* __restrict__ Wk,
    ushort* __restrict__ qhi, ushort* __restrict__ qlo,
    ushort* __restrict__ khi, ushort* __restrict__ klo,
    ushort* __restrict__ wqthi, ushort* __restrict__ wqtlo,
    ushort* __restrict__ wkthi, ushort* __restrict__ wktlo)
{
  __shared__ float t[64][65];
  const int bid = blockIdx.x, tid = threadIdx.x;
  if (bid < 1024) {
    const int z = bid >> 9;
    const float* in = z ? keys : query;
    ushort* hi = z ? khi : qhi;
    ushort* lo = z ? klo : qlo;
    const size_t i = ((size_t)(bid & 511) * 256 + tid) * 4;
    float4 v = *(const float4*)(in + i);
    ushort h0, h1, h2, h3, l0, l1, l2, l3;
    split1(v.x, h0, l0); split1(v.y, h1, l1);
    split1(v.z, h2, l2); split1(v.w, h3, l3);
    *(ushort4*)(hi + i) = make_ushort4(h0, h1, h2, h3);
    *(ushort4*)(lo + i) = make_ushort4(l0, l1, l2, l3);
  } else {
    const int idx = bid - 1024;
    const int z = idx >> 8;
    const float* W = z ? Wk : Wq;
    ushort* thi = z ? wkthi : wqthi;
    ushort* tlo = z ? wktlo : wqtlo;
    const int n0 = (idx & 15) * 64, h0 = ((idx >> 4) & 15) * 64;
    const int r = tid >> 4, c = (tid & 15) * 4;
#pragma unroll
    for (int i = 0; i < 4; ++i) {
      const int rr = r + i * 16;
      float4 wv = *(const float4*)(W + (size_t)(h0 + rr) * 1024 + n0 + c);
      t[rr][c + 0] = wv.x; t[rr][c + 1] = wv.y;
      t[rr][c + 2] = wv.z; t[rr][c + 3] = wv.w;
    }
    __syncthreads();
#pragma unroll
    for (int i = 0; i < 4; ++i) {
      const int rr = r + i * 16;
      ushort h0v, h1v, h2v, h3v, l0v, l1v, l2v, l3v;
      split1(t[c + 0][rr] * TANH_SCALE, h0v, l0v);
      split1(t[c + 1][rr] * TANH_SCALE, h1v, l1v);
      split1(t[c + 2][rr] * TANH_SCALE, h2v, l2v);
      split1(t[c + 3][rr] * TANH_SCALE, h3v, l3v);
      *(ushort4*)(thi + (size_t)(n0 + rr) * 1024 + h0 + c) = make_ushort4(h0v, h1v, h2v, h3v);
      *(ushort4*)(tlo + (size_t)(n0 + rr) * 1024 + h0 + c) = make_ushort4(l0v, l1v, l2v, l3v);
    }
  }
}

// ---------------- Kernel 2: MFMA GEMM, 3-term bf16 split; factored epilogue ----------------
__global__ __launch_bounds__(256) void gemm_mfma(
    const ushort* __restrict__ qhi, const ushort* __restrict__ qlo,
    const ushort* __restrict__ khi, const ushort* __restrict__ klo,
    const ushort* __restrict__ wqthi, const ushort* __restrict__ wqtlo,
    const ushort* __restrict__ wkthi, const ushort* __restrict__ wktlo,
    float* __restrict__ MQ, int* __restrict__ IQ,
    float* __restrict__ MKT, int* __restrict__ IKT)
{
  const int z = blockIdx.y;
  const int bid = blockIdx.x;
  int m0, n0, ldc;
  const ushort *Ah_g, *Al_g, *Bh_g, *Bl_g;
  float* Mp; int* Ip;
  if (z == 0) {             // MQ/IQ [512][1024]
    m0 = (bid >> 4) * 64; n0 = (bid & 15) * 64; ldc = 1024;
    Ah_g = qhi; Al_g = qlo; Bh_g = wqthi; Bl_g = wqtlo; Mp = MQ; Ip = IQ;
  } else {                  // MKT/IKT [1024][512]
    m0 = (bid >> 3) * 64; n0 = (bid & 7) * 64; ldc = 512;
    Ah_g = wkthi; Al_g = wktlo; Bh_g = khi; Bl_g = klo; Mp = MKT; Ip = IKT;
  }

  __shared__ __align__(16) ushort Ah[64 * 40];
  __shared__ __align__(16) ushort Al[64 * 40];
  __shared__ __align__(16) ushort Bh[64 * 40];
  __shared__ __align__(16) ushort Bl[64 * 40];

  const int tid = threadIdx.x;
  const int srow = tid >> 2, skc = (tid & 3) * 8;
  const size_t gA = (size_t)(m0 + srow) * 1024 + skc;
  const size_t gB = (size_t)(n0 + srow) * 1024 + skc;
  const int soff = srow * 40 + skc;

  uint4 rah = *(const uint4*)(Ah_g + gA);
  uint4 ral = *(const uint4*)(Al_g + gA);
  uint4 rbh = *(const uint4*)(Bh_g + gB);
  uint4 rbl = *(const uint4*)(Bl_g + gB);

  const int w = __builtin_amdgcn_readfirstlane(tid >> 6);
  const int lane = tid & 63;
  const int wm = (w >> 1) * 32, wn = (w & 1) * 32;
  const int fr = lane & 15, kg = lane >> 4;
  const int aoff = (wm + fr) * 40 + kg * 8;
  const int boff = (wn + fr) * 40 + kg * 8;

  f32x4_t acc[2][2] = {};

  for (int kk = 0; kk < 1024; kk += 32) {
    __syncthreads();
    *(uint4*)(Ah + soff) = rah;
    *(uint4*)(Al + soff) = ral;
    *(uint4*)(Bh + soff) = rbh;
    *(uint4*)(Bl + soff) = rbl;
    __syncthreads();

    if (kk + 32 < 1024) {
      rah = *(const uint4*)(Ah_g + gA + kk + 32);
      ral = *(const uint4*)(Al_g + gA + kk + 32);
      rbh = *(const uint4*)(Bh_g + gB + kk + 32);
      rbl = *(const uint4*)(Bl_g + gB + kk + 32);
    }

    bf16x8_t ah0 = *(const bf16x8_t*)(Ah + aoff);
    bf16x8_t ah1 = *(const bf16x8_t*)(Ah + aoff + 16 * 40);
    bf16x8_t al0 = *(const bf16x8_t*)(Al + aoff);
    bf16x8_t al1 = *(const bf16x8_t*)(Al + aoff + 16 * 40);
    bf16x8_t bh0 = *(const bf16x8_t*)(Bh + boff);
    bf16x8_t bh1 = *(const bf16x8_t*)(Bh + boff + 16 * 40);
    bf16x8_t bl0 = *(const bf16x8_t*)(Bl + boff);
    bf16x8_t bl1 = *(const bf16x8_t*)(Bl + boff + 16 * 40);

    acc[0][0] = __builtin_amdgcn_mfma_f32_16x16x32_bf16(ah0, bh0, acc[0][0], 0, 0, 0);
    acc[0][1] = __builtin_amdgcn_mfma_f32_16x16x32_bf16(ah0, bh1, acc[0][1], 0, 0, 0);
    acc[1][0] = __builtin_amdgcn_mfma_f32_16x16x32_bf16(ah1, bh0, acc[1][0], 0, 0, 0);
    acc[1][1] = __builtin_amdgcn_mfma_f32_16x16x32_bf16(ah1, bh1, acc[1][1], 0, 0, 0);
    acc[0][0] = __builtin_amdgcn_mfma_f32_16x16x32_bf16(ah0, bl0, acc[0][0], 0, 0, 0);
    acc[0][1] = __builtin_amdgcn_mfma_f32_16x16x32_bf16(ah0, bl1, acc[0][1], 0, 0, 0);
    acc[1][0] = __builtin_amdgcn_mfma_f32_16x16x32_bf16(ah1, bl0, acc[1][0], 0, 0, 0);
    acc[1][1] = __builtin_amdgcn_mfma_f32_16x16x32_bf16(ah1, bl1, acc[1][1], 0, 0, 0);
    acc[0][0] = __builtin_amdgcn_mfma_f32_16x16x32_bf16(al0, bh0, acc[0][0], 0, 0, 0);
    acc[0][1] = __builtin_amdgcn_mfma_f32_16x16x32_bf16(al0, bh1, acc[0][1], 0, 0, 0);
    acc[1][0] = __builtin_amdgcn_mfma_f32_16x16x32_bf16(al1, bh0, acc[1][0], 0, 0, 0);
    acc[1][1] = __builtin_amdgcn_mfma_f32_16x16x32_bf16(al1, bh1, acc[1][1], 0, 0, 0);
  }

#pragma unroll
  for (int fm = 0; fm < 2; ++fm)
#pragma unroll
    for (int fn = 0; fn < 2; ++fn) {
      const int col = n0 + wn + fn * 16 + fr;
#pragma unroll
      for (int j = 0; j < 4; ++j) {
        const int row = m0 + wm + fm * 16 + kg * 4 + j;
        const float a = acc[fm][fn][j];
        const float fa = floorf(a);
        Mp[(size_t)row * ldc + col] = __builtin_amdgcn_exp2f(a - fa);  // in [1,2)
        Ip[(size_t)row * ldc + col] = (int)fa;
      }
    }
}

// ---------------- Kernel 3: fused attn, factored exponent, plain-plane loads ----------------
// grid 512: block = (b,h) = bid>>5, q-tile = (bid&31)*8. Wave w: k = w*64+lane (1 k/lane).
// mk/ik chunk (8 d) in regs, reused across 8 q. mq/iq/Va wave-uniform.
// Per element: u=mq*mk; n=iq+ik; t=ldexp(u,n); r=rcp(t+1); acc+=va*r.  [5 VALU + 1 trans]
__global__ __launch_bounds__(256) void attn_fused(
    const float* __restrict__ MQ, const int* __restrict__ IQ,
    const float* __restrict__ MKT, const int* __restrict__ IKT,
    const float* __restrict__ Va, const int* __restrict__ mask,
    const float* __restrict__ values,
    float* __restrict__ weights, float* __restrict__ ctx)
{
  __shared__ float red_m[4][8];
  __shared__ float red_s[4][8];
  __shared__ __align__(16) float P_lds[8][256];

  const int tid = threadIdx.x;
  const int lane = tid & 63;
  const int w = __builtin_amdgcn_readfirstlane(tid >> 6);
  const int bid = blockIdx.x;
  const int bh = bid >> 5;
  const int b = bh & 1, h = bh >> 1;
  const int qt = (bid & 31) * 8;
  const int k = w * 64 + lane;

  const float pen = 99.0f * (1.0f - (float)mask[b * 256 + k]);

  float ssum = Va[h * 128 + lane] + Va[h * 128 + 64 + lane];
#pragma unroll
  for (int off = 32; off; off >>= 1) ssum += __shfl_xor(ssum, off, 64);

  const float* mkp = MKT + (size_t)(h * 128) * 512 + b * 256 + k;   // + d*512 (per-lane)
  const int*   ikp = IKT + (size_t)(h * 128) * 512 + b * 256 + k;
  const float* mqb = MQ + (size_t)(b * 256 + qt) * 1024 + h * 128;  // + q*1024 + d (uniform)
  const int*   iqb = IQ + (size_t)(b * 256 + qt) * 1024 + h * 128;
  const float* vap = Va + h * 128;                                  // uniform

  float acc[8] = {0.f, 0.f, 0.f, 0.f, 0.f, 0.f, 0.f, 0.f};

  float mkc[8]; int ikc[8];
#pragma unroll
  for (int j = 0; j < 8; ++j) mkc[j] = mkp[(size_t)j * 512];
#pragma unroll
  for (int j = 0; j < 8; ++j) ikc[j] = ikp[(size_t)j * 512];

  for (int ch = 0; ch < 16; ++ch) {   // 16 chunks x 8 d
    const int d0 = ch * 8;
    float mkn[8]; int ikn[8];
    if (ch < 15) {  // prefetch next chunk; consumed after the full 8-q pass
#pragma unroll
      for (int j = 0; j < 8; ++j) mkn[j] = mkp[(size_t)(d0 + 8 + j) * 512];
#pragma unroll
      for (int j = 0; j < 8; ++j) ikn[j] = ikp[(size_t)(d0 + 8 + j) * 512];
    }
#pragma unroll
    for (int q = 0; q < 8; ++q) {
      const float* mqq = mqb + (size_t)q * 1024 + d0;   // wave-uniform
      const int*   iqq = iqb + (size_t)q * 1024 + d0;
      float4 mqa = *(const float4*)(mqq + 0);
      float4 mqbv = *(const float4*)(mqq + 4);
      int4 iqa = *(const int4*)(iqq + 0);
      int4 iqbv = *(const int4*)(iqq + 4);
      float4 vaa = *(const float4*)(vap + d0 + 0);
      float4 vab = *(const float4*)(vap + d0 + 4);
#pragma unroll
      for (int e = 0; e < 8; ++e) {
        const float mq = (e == 0) ? mqa.x : (e == 1) ? mqa.y : (e == 2) ? mqa.z :
                         (e == 3) ? mqa.w : (e == 4) ? mqbv.x : (e == 5) ? mqbv.y :
                         (e == 6) ? mqbv.z : mqbv.w;
        const int iq = (e == 0) ? iqa.x : (e == 1) ? iqa.y : (e == 2) ? iqa.z :
                       (e == 3) ? iqa.w : (e == 4) ? iqbv.x : (e == 5) ? iqbv.y :
                       (e == 6) ? iqbv.z : iqbv.w;
        const float va = (e == 0) ? vaa.x : (e == 1) ? vaa.y : (e == 2) ? vaa.z :
                         (e == 3) ? vaa.w : (e == 4) ? vab.x : (e == 5) ? vab.y :
                         (e == 6) ? vab.z : vab.w;
        const float u = mq * mkc[e];
        const int   n = iq + ikc[e];
        const float t = ldexpf(u, n);           // v_ldexp_f32, full-rate; inf/0 saturate right
        acc[q] += va * __builtin_amdgcn_rcpf(t + 1.0f);
      }
    }
    if (ch < 15) {
#pragma unroll
      for (int j = 0; j < 8; ++j) { mkc[j] = mkn[j]; ikc[j] = ikn[j]; }
    }
  }

  // logits
  float l[8], p[8];
#pragma unroll
  for (int q = 0; q < 8; ++q) l[q] = ssum - 2.0f * acc[q] - pen;

  // row max: wave-reduce then cross-wave via LDS
#pragma unroll
  for (int q = 0; q < 8; ++q) {
    float m = l[q];
#pragma unroll
    for (int off = 32; off; off >>= 1) m = fmaxf(m, __shfl_xor(m, off, 64));
    if (lane == 0) red_m[w][q] = m;
  }
  __syncthreads();
#pragma unroll
  for (int q = 0; q < 8; ++q) {
    float m = fmaxf(fmaxf(red_m[0][q], red_m[1][q]), fmaxf(red_m[2][q], red_m[3][q]));
    p[q] = __builtin_amdgcn_exp2f((l[q] - m) * LOG2E);
  }
#pragma unroll
  for (int q = 0; q < 8; ++q) {
    float s = p[q];
#pragma unroll
    for (int off = 32; off; off >>= 1) s += __shfl_xor(s, off, 64);
    if (lane == 0) red_s[w][q] = s;
  }
  __syncthreads();
#pragma unroll
  for (int q = 0; q < 8; ++q) {
    const float s = (red_s[0][q] + red_s[1][q]) + (red_s[2][q] + red_s[3][q]);
    const float pq = p[q] / s;
    weights[((size_t)((b * 8 + h) * 256) + qt + q) * 256 + k] = pq;
    P_lds[q][k] = pq;
  }
  __syncthreads();

  // PV: wave w -> q rows {2w, 2w+1}; lane: d4 = lane&31, ks = lane>>5 (k-half).
  const int d4 = lane & 31, ks = lane >> 5;
  const int q0 = w * 2, q1 = q0 + 1;
  const float* vb = values + (size_t)(b * 256 + ks * 128) * 1024 + h * 128 + d4 * 4;
  float4 A0 = make_float4(0, 0, 0, 0), A1 = make_float4(0, 0, 0, 0);
#pragma unroll 2
  for (int k4 = 0; k4 < 32; ++k4) {
    float4 p0v = *(const float4*)&P_lds[q0][ks * 128 + k4 * 4];
    float4 p1v = *(const float4*)&P_lds[q1][ks * 128 + k4 * 4];
#pragma unroll
    for (int j = 0; j < 4; ++j) {
      float4 v = *(const float4*)(vb + (size_t)(k4 * 4 + j) * 1024);
      const float pj0 = (j == 0) ? p0v.x : (j == 1) ? p0v.y : (j == 2) ? p0v.z : p0v.w;
      const float pj1 = (j == 0) ? p1v.x : (j == 1) ? p1v.y : (j == 2) ? p1v.z : p1v.w;
      A0.x += pj0 * v.x; A0.y += pj0 * v.y; A0.z += pj0 * v.z; A0.w += pj0 * v.w;
      A1.x += pj1 * v.x; A1.y += pj1 * v.y; A1.z += pj1 * v.z; A1.w += pj1 * v.w;
    }
  }
  A0.x += __shfl_xor(A0.x, 32, 64); A0.y += __shfl_xor(A0.y, 32, 64);
  A0.z += __shfl_xor(A0.z, 32, 64); A0.w += __shfl_xor(A0.w, 32, 64);
  A1.x += __shfl_xor(A1.x, 32, 64); A1.y += __shfl_xor(A1.y, 32, 64);
  A1.z += __shfl_xor(A1.z, 32, 64); A1.w += __shfl_xor(A1.w, 32, 64);
  if (lane < 32) {
    *(float4*)&ctx[(size_t)(b * 256 + qt + q0) * 1024 + h * 128 + d4 * 4] = A0;
    *(float4*)&ctx[(size_t)(b * 256 + qt + q1) * 1024 + h * 128 + d4 * 4] = A1;
  }
}

extern "C" void kernel_launch(void* const* d_in, const int* in_sizes, int n_in,
                              void* d_out, int out_size, void* d_ws, size_t ws_size,
                              hipStream_t stream) {
  const float* query  = (const float*)d_in[0];
  const float* keys   = (const float*)d_in[1];
  const float* values = (const float*)d_in[2];
  const int*   mask   = (const int*)d_in[3];
  const float* Wq     = (const float*)d_in[4];
  const float* Wk     = (const float*)d_in[5];
  const float* Va     = (const float*)d_in[6];

  float* ctx     = (float*)d_out;            // [2,256,1024]
  float* weights = ctx + 524288;             // [2,8,256,256]

  // ws layout (ws_size = 256 MiB; we use 20 MB):
  ushort* qhi   = (ushort*)d_ws;             // 1 MB each
  ushort* qlo   = qhi + 524288;
  ushort* khi   = qlo + 524288;
  ushort* klo   = khi + 524288;
  ushort* wqthi = klo + 524288;              // 2 MB each
  ushort* wqtlo = wqthi + 1048576;
  ushort* wkthi = wqtlo + 1048576;
  ushort* wktlo = wkthi + 1048576;
  float*  MQ    = (float*)(wktlo + 1048576); // [512][1024] f32 (2 MB)
  int*    IQ    = (int*)(MQ + 524288);       // [512][1024] i32 (2 MB)
  float*  MKT   = (float*)(IQ + 524288);     // [1024][512] f32 (2 MB)
  int*    IKT   = (int*)(MKT + 524288);      // [1024][512] i32 (2 MB)

  prep<<<dim3(1536), 256, 0, stream>>>(query, keys, Wq, Wk,
                                       qhi, qlo, khi, klo,
                                       wqthi, wqtlo, wkthi, wktlo);
  gemm_mfma<<<dim3(128, 2), 256, 0, stream>>>(qhi, qlo, khi, klo,
                                              wqthi, wqtlo, wkthi, wktlo,
                                              MQ, IQ, MKT, IKT);
  attn_fused<<<dim3(512), 256, 0, stream>>>(MQ, IQ, MKT, IKT,
                                            Va, mask, values, weights, ctx);
}

// Round 12
// 67.155 us; speedup vs baseline: 1.2842x; 1.2376x over previous
//
#include <hip/hip_runtime.h>
#include <hip/hip_bf16.h>

// MultiHeadAttention (additive/Bahdanau): B=2, Q=K=256, HIDDEN=1024, 8 heads x 128
// Pipeline (3 kernels):
//  1) prep:      split query/keys -> bf16 hi/lo; W^T*2log2e -> bf16 hi/lo (LDS transpose)
//  2) gemm_mfma: 3-term bf16 MFMA GEMMs; epilogue stores g = 2^(a/8) (single f32 plane/side):
//                GQ [512][1024], GKT [1024][512] (transposed free).
//  3) attn_fused: t = e^{2x} = (gq*gk)^8 via 3 squarings; r = rcp(t+1); tanh = 1-2r.
//                 [7 VALU + 1 trans/elem, no ldexp/int/unpack]. gq-tile + Va staged in LDS
//                 (broadcast ds_read; no scalar-load latency exposure). Softmax+PV fused (R8).
// Overflow is self-saturating: any squaring -> inf/0 -> r -> 0/1 = tanh's +-1 limits.
// ws_size = 256 MiB (observed); we use ~16 MB.

#define TANH_SCALE 2.88539008177792681472f   // 2*log2(e)
#define LOG2E      1.44269504088896340736f

typedef __attribute__((ext_vector_type(8))) short bf16x8_t;   // 8 bf16 = 4 VGPRs
typedef __attribute__((ext_vector_type(4))) float f32x4_t;

__device__ inline ushort bf16_rne(float f) {
  unsigned u = __float_as_uint(f);
  u += 0x7FFFu + ((u >> 16) & 1u);
  return (ushort)(u >> 16);
}
__device__ inline float bf16_to_f(ushort h) { return __uint_as_float((unsigned)h << 16); }
__device__ inline void split1(float v, ushort& hi, ushort& lo) {
  hi = bf16_rne(v);
  lo = bf16_rne(v - bf16_to_f(hi));
}

// ---------------- Kernel 1: prep (unchanged) ----------------
__global__ __launch_bounds__(256) void prep(
    const float* __restrict__ query, const float* __restrict__ keys,
    const float* __restrict__ Wq, const float* __restrict__ Wk,
    ushort* __restrict__ qhi, ushort* __restrict__ qlo,
    ushort* __restrict__ khi, ushort* __restrict__ klo,
    ushort* __restrict__ wqthi, ushort* __restrict__ wqtlo,
    ushort* __restrict__ wkthi, ushort* __restrict__ wktlo)
{
  __shared__ float t[64][65];
  const int bid = blockIdx.x, tid = threadIdx.x;
  if (bid < 1024) {
    const int z = bid >> 9;
    const float* in = z ? keys : query;
    ushort* hi = z ? khi : qhi;
    ushort* lo = z ? klo : qlo;
    const size_t i = ((size_t)(bid & 511) * 256 + tid) * 4;
    float4 v = *(const float4*)(in + i);
    ushort h0, h1, h2, h3, l0, l1, l2, l3;
    split1(v.x, h0, l0); split1(v.y, h1, l1);
    split1(v.z, h2, l2); split1(v.w, h3, l3);
    *(ushort4*)(hi + i) = make_ushort4(h0, h1, h2, h3);
    *(ushort4*)(lo + i) = make_ushort4(l0, l1, l2, l3);
  } else {
    const int idx = bid - 1024;
    const int z = idx >> 8;
    const float* W = z ? Wk : Wq;
    ushort* thi = z ? wkthi : wqthi;
    ushort* tlo = z ? wktlo : wqtlo;
    const int n0 = (idx & 15) * 64, h0 = ((idx >> 4) & 15) * 64;
    const int r = tid >> 4, c = (tid & 15) * 4;
#pragma unroll
    for (int i = 0; i < 4; ++i) {
      const int rr = r + i * 16;
      float4 wv = *(const float4*)(W + (size_t)(h0 + rr) * 1024 + n0 + c);
      t[rr][c + 0] = wv.x; t[rr][c + 1] = wv.y;
      t[rr][c + 2] = wv.z; t[rr][c + 3] = wv.w;
    }
    __syncthreads();
#pragma unroll
    for (int i = 0; i < 4; ++i) {
      const int rr = r + i * 16;
      ushort h0v, h1v, h2v, h3v, l0v, l1v, l2v, l3v;
      split1(t[c + 0][rr] * TANH_SCALE, h0v, l0v);
      split1(t[c + 1][rr] * TANH_SCALE, h1v, l1v);
      split1(t[c + 2][rr] * TANH_SCALE, h2v, l2v);
      split1(t[c + 3][rr] * TANH_SCALE, h3v, l3v);
      *(ushort4*)(thi + (size_t)(n0 + rr) * 1024 + h0 + c) = make_ushort4(h0v, h1v, h2v, h3v);
      *(ushort4*)(tlo + (size_t)(n0 + rr) * 1024 + h0 + c) = make_ushort4(l0v, l1v, l2v, l3v);
    }
  }
}

// ---------------- Kernel 2: MFMA GEMM, 3-term bf16 split; g = 2^(a/8) epilogue ----------------
__global__ __launch_bounds__(256) void gemm_mfma(
    const ushort* __restrict__ qhi, const ushort* __restrict__ qlo,
    const ushort* __restrict__ khi, const ushort* __restrict__ klo,
    const ushort* __restrict__ wqthi, const ushort* __restrict__ wqtlo,
    const ushort* __restrict__ wkthi, const ushort* __restrict__ wktlo,
    float* __restrict__ GQ, float* __restrict__ GKT)
{
  const int z = blockIdx.y;
  const int bid = blockIdx.x;
  int m0, n0, ldc;
  const ushort *Ah_g, *Al_g, *Bh_g, *Bl_g;
  float* Gp;
  if (z == 0) {             // GQ [512][1024]
    m0 = (bid >> 4) * 64; n0 = (bid & 15) * 64; ldc = 1024;
    Ah_g = qhi; Al_g = qlo; Bh_g = wqthi; Bl_g = wqtlo; Gp = GQ;
  } else {                  // GKT [1024][512]
    m0 = (bid >> 3) * 64; n0 = (bid & 7) * 64; ldc = 512;
    Ah_g = wkthi; Al_g = wktlo; Bh_g = khi; Bl_g = klo; Gp = GKT;
  }

  __shared__ __align__(16) ushort Ah[64 * 40];
  __shared__ __align__(16) ushort Al[64 * 40];
  __shared__ __align__(16) ushort Bh[64 * 40];
  __shared__ __align__(16) ushort Bl[64 * 40];

  const int tid = threadIdx.x;
  const int srow = tid >> 2, skc = (tid & 3) * 8;
  const size_t gA = (size_t)(m0 + srow) * 1024 + skc;
  const size_t gB = (size_t)(n0 + srow) * 1024 + skc;
  const int soff = srow * 40 + skc;

  uint4 rah = *(const uint4*)(Ah_g + gA);
  uint4 ral = *(const uint4*)(Al_g + gA);
  uint4 rbh = *(const uint4*)(Bh_g + gB);
  uint4 rbl = *(const uint4*)(Bl_g + gB);

  const int w = __builtin_amdgcn_readfirstlane(tid >> 6);
  const int lane = tid & 63;
  const int wm = (w >> 1) * 32, wn = (w & 1) * 32;
  const int fr = lane & 15, kg = lane >> 4;
  const int aoff = (wm + fr) * 40 + kg * 8;
  const int boff = (wn + fr) * 40 + kg * 8;

  f32x4_t acc[2][2] = {};

  for (int kk = 0; kk < 1024; kk += 32) {
    __syncthreads();
    *(uint4*)(Ah + soff) = rah;
    *(uint4*)(Al + soff) = ral;
    *(uint4*)(Bh + soff) = rbh;
    *(uint4*)(Bl + soff) = rbl;
    __syncthreads();

    if (kk + 32 < 1024) {
      rah = *(const uint4*)(Ah_g + gA + kk + 32);
      ral = *(const uint4*)(Al_g + gA + kk + 32);
      rbh = *(const uint4*)(Bh_g + gB + kk + 32);
      rbl = *(const uint4*)(Bl_g + gB + kk + 32);
    }

    bf16x8_t ah0 = *(const bf16x8_t*)(Ah + aoff);
    bf16x8_t ah1 = *(const bf16x8_t*)(Ah + aoff + 16 * 40);
    bf16x8_t al0 = *(const bf16x8_t*)(Al + aoff);
    bf16x8_t al1 = *(const bf16x8_t*)(Al + aoff + 16 * 40);
    bf16x8_t bh0 = *(const bf16x8_t*)(Bh + boff);
    bf16x8_t bh1 = *(const bf16x8_t*)(Bh + boff + 16 * 40);
    bf16x8_t bl0 = *(const bf16x8_t*)(Bl + boff);
    bf16x8_t bl1 = *(const bf16x8_t*)(Bl + boff + 16 * 40);

    acc[0][0] = __builtin_amdgcn_mfma_f32_16x16x32_bf16(ah0, bh0, acc[0][0], 0, 0, 0);
    acc[0][1] = __builtin_amdgcn_mfma_f32_16x16x32_bf16(ah0, bh1, acc[0][1], 0, 0, 0);
    acc[1][0] = __builtin_amdgcn_mfma_f32_16x16x32_bf16(ah1, bh0, acc[1][0], 0, 0, 0);
    acc[1][1] = __builtin_amdgcn_mfma_f32_16x16x32_bf16(ah1, bh1, acc[1][1], 0, 0, 0);
    acc[0][0] = __builtin_amdgcn_mfma_f32_16x16x32_bf16(ah0, bl0, acc[0][0], 0, 0, 0);
    acc[0][1] = __builtin_amdgcn_mfma_f32_16x16x32_bf16(ah0, bl1, acc[0][1], 0, 0, 0);
    acc[1][0] = __builtin_amdgcn_mfma_f32_16x16x32_bf16(ah1, bl0, acc[1][0], 0, 0, 0);
    acc[1][1] = __builtin_amdgcn_mfma_f32_16x16x32_bf16(ah1, bl1, acc[1][1], 0, 0, 0);
    acc[0][0] = __builtin_amdgcn_mfma_f32_16x16x32_bf16(al0, bh0, acc[0][0], 0, 0, 0);
    acc[0][1] = __builtin_amdgcn_mfma_f32_16x16x32_bf16(al0, bh1, acc[0][1], 0, 0, 0);
    acc[1][0] = __builtin_amdgcn_mfma_f32_16x16x32_bf16(al1, bh0, acc[1][0], 0, 0, 0);
    acc[1][1] = __builtin_amdgcn_mfma_f32_16x16x32_bf16(al1, bh1, acc[1][1], 0, 0, 0);
  }

#pragma unroll
  for (int fm = 0; fm < 2; ++fm)
#pragma unroll
    for (int fn = 0; fn < 2; ++fn) {
      const int col = n0 + wn + fn * 16 + fr;
#pragma unroll
      for (int j = 0; j < 4; ++j) {
        const int row = m0 + wm + fm * 16 + kg * 4 + j;
        Gp[(size_t)row * ldc + col] = __builtin_amdgcn_exp2f(acc[fm][fn][j] * 0.125f);
      }
    }
}

// ---------------- Kernel 3: fused attn, eighth-root planes, LDS-staged uniforms ----------------
// grid 512: block = (b,h) = bid>>5, q-tile = (bid&31)*8. Wave w: k = w*64+lane (1 k/lane).
// gk chunk (8 d) in regs (reuse x8 q); gq tile + Va in LDS (broadcast ds_read).
// Per elem: u=gq*gk; t=((u^2)^2)^2; r=rcp(t+1); acc+=va*r.  [7 VALU + 1 trans]
__global__ __launch_bounds__(256) void attn_fused(
    const float* __restrict__ GQ, const float* __restrict__ GKT,
    const float* __restrict__ Va, const int* __restrict__ mask,
    const float* __restrict__ values,
    float* __restrict__ weights, float* __restrict__ ctx)
{
  __shared__ __align__(16) float gq_s[8][128];
  __shared__ __align__(16) float va_s[128];
  __shared__ float red_m[4][8];
  __shared__ float red_s[4][8];
  __shared__ __align__(16) float P_lds[8][256];

  const int tid = threadIdx.x;
  const int lane = tid & 63;
  const int w = __builtin_amdgcn_readfirstlane(tid >> 6);
  const int bid = blockIdx.x;
  const int bh = bid >> 5;
  const int b = bh & 1, h = bh >> 1;
  const int qt = (bid & 31) * 8;
  const int k = w * 64 + lane;

  // stage gq tile (8x128) + Va head slice into LDS
  {
    const int sq = tid >> 5, sd = (tid & 31) * 4;
    *(float4*)&gq_s[sq][sd] =
        *(const float4*)(GQ + (size_t)(b * 256 + qt + sq) * 1024 + h * 128 + sd);
    if (tid < 32) *(float4*)&va_s[tid * 4] = *(const float4*)(Va + h * 128 + tid * 4);
  }

  const float pen = 99.0f * (1.0f - (float)mask[b * 256 + k]);

  float ssum = Va[h * 128 + lane] + Va[h * 128 + 64 + lane];
#pragma unroll
  for (int off = 32; off; off >>= 1) ssum += __shfl_xor(ssum, off, 64);

  const float* gkp = GKT + (size_t)(h * 128) * 512 + b * 256 + k;   // + d*512 (per-lane)

  __syncthreads();

  float acc0[8] = {0.f, 0.f, 0.f, 0.f, 0.f, 0.f, 0.f, 0.f};
  float acc1[8] = {0.f, 0.f, 0.f, 0.f, 0.f, 0.f, 0.f, 0.f};

  float gkc[8];
#pragma unroll
  for (int j = 0; j < 8; ++j) gkc[j] = gkp[(size_t)j * 512];

  for (int ch = 0; ch < 16; ++ch) {   // 16 chunks x 8 d
    const int d0 = ch * 8;
    float gkn[8];
    if (ch < 15) {  // prefetch next gk chunk; consumed after the full 8-q pass
#pragma unroll
      for (int j = 0; j < 8; ++j) gkn[j] = gkp[(size_t)(d0 + 8 + j) * 512];
    }
    float var_[8];
    *(float4*)&var_[0] = *(const float4*)&va_s[d0];
    *(float4*)&var_[4] = *(const float4*)&va_s[d0 + 4];
#pragma unroll
    for (int q = 0; q < 8; ++q) {
      float gqr[8];
      *(float4*)&gqr[0] = *(const float4*)&gq_s[q][d0];       // broadcast ds_read_b128
      *(float4*)&gqr[4] = *(const float4*)&gq_s[q][d0 + 4];
#pragma unroll
      for (int e = 0; e < 8; ++e) {
        const float u  = gqr[e] * gkc[e];
        const float u2 = u * u;
        const float u4 = u2 * u2;
        const float t  = u4 * u4;                              // = e^{2x}; inf/0 saturate right
        const float r  = __builtin_amdgcn_rcpf(t + 1.0f);
        if (e & 1) acc1[q] += var_[e] * r; else acc0[q] += var_[e] * r;
      }
    }
    if (ch < 15) {
#pragma unroll
      for (int j = 0; j < 8; ++j) gkc[j] = gkn[j];
    }
  }

  // logits
  float l[8], p[8];
#pragma unroll
  for (int q = 0; q < 8; ++q) l[q] = ssum - 2.0f * (acc0[q] + acc1[q]) - pen;

  // row max: wave-reduce then cross-wave via LDS
#pragma unroll
  for (int q = 0; q < 8; ++q) {
    float m = l[q];
#pragma unroll
    for (int off = 32; off; off >>= 1) m = fmaxf(m, __shfl_xor(m, off, 64));
    if (lane == 0) red_m[w][q] = m;
  }
  __syncthreads();
#pragma unroll
  for (int q = 0; q < 8; ++q) {
    float m = fmaxf(fmaxf(red_m[0][q], red_m[1][q]), fmaxf(red_m[2][q], red_m[3][q]));
    p[q] = __builtin_amdgcn_exp2f((l[q] - m) * LOG2E);
  }
#pragma unroll
  for (int q = 0; q < 8; ++q) {
    float s = p[q];
#pragma unroll
    for (int off = 32; off; off >>= 1) s += __shfl_xor(s, off, 64);
    if (lane == 0) red_s[w][q] = s;
  }
  __syncthreads();
#pragma unroll
  for (int q = 0; q < 8; ++q) {
    const float s = (red_s[0][q] + red_s[1][q]) + (red_s[2][q] + red_s[3][q]);
    const float pq = p[q] / s;
    weights[((size_t)((b * 8 + h) * 256) + qt + q) * 256 + k] = pq;
    P_lds[q][k] = pq;
  }
  __syncthreads();

  // PV: wave w -> q rows {2w, 2w+1}; lane: d4 = lane&31, ks = lane>>5 (k-half).
  const int d4 = lane & 31, ks = lane >> 5;
  const int q0 = w * 2, q1 = q0 + 1;
  const float* vb = values + (size_t)(b * 256 + ks * 128) * 1024 + h * 128 + d4 * 4;
  float4 A0 = make_float4(0, 0, 0, 0), A1 = make_float4(0, 0, 0, 0);
#pragma unroll 2
  for (int k4 = 0; k4 < 32; ++k4) {
    float4 p0v = *(const float4*)&P_lds[q0][ks * 128 + k4 * 4];
    float4 p1v = *(const float4*)&P_lds[q1][ks * 128 + k4 * 4];
#pragma unroll
    for (int j = 0; j < 4; ++j) {
      float4 v = *(const float4*)(vb + (size_t)(k4 * 4 + j) * 1024);
      const float pj0 = (j == 0) ? p0v.x : (j == 1) ? p0v.y : (j == 2) ? p0v.z : p0v.w;
      const float pj1 = (j == 0) ? p1v.x : (j == 1) ? p1v.y : (j == 2) ? p1v.z : p1v.w;
      A0.x += pj0 * v.x; A0.y += pj0 * v.y; A0.z += pj0 * v.z; A0.w += pj0 * v.w;
      A1.x += pj1 * v.x; A1.y += pj1 * v.y; A1.z += pj1 * v.z; A1.w += pj1 * v.w;
    }
  }
  A0.x += __shfl_xor(A0.x, 32, 64); A0.y += __shfl_xor(A0.y, 32, 64);
  A0.z += __shfl_xor(A0.z, 32, 64); A0.w += __shfl_xor(A0.w, 32, 64);
  A1.x += __shfl_xor(A1.x, 32, 64); A1.y += __shfl_xor(A1.y, 32, 64);
  A1.z += __shfl_xor(A1.z, 32, 64); A1.w += __shfl_xor(A1.w, 32, 64);
  if (lane < 32) {
    *(float4*)&ctx[(size_t)(b * 256 + qt + q0) * 1024 + h * 128 + d4 * 4] = A0;
    *(float4*)&ctx[(size_t)(b * 256 + qt + q1) * 1024 + h * 128 + d4 * 4] = A1;
  }
}

extern "C" void kernel_launch(void* const* d_in, const int* in_sizes, int n_in,
                              void* d_out, int out_size, void* d_ws, size_t ws_size,
                              hipStream_t stream) {
  const float* query  = (const float*)d_in[0];
  const float* keys   = (const float*)d_in[1];
  const float* values = (const float*)d_in[2];
  const int*   mask   = (const int*)d_in[3];
  const float* Wq     = (const float*)d_in[4];
  const float* Wk     = (const float*)d_in[5];
  const float* Va     = (const float*)d_in[6];

  float* ctx     = (float*)d_out;            // [2,256,1024]
  float* weights = ctx + 524288;             // [2,8,256,256]

  // ws layout (~16 MB used):
  ushort* qhi   = (ushort*)d_ws;             // 1 MB each
  ushort* qlo   = qhi + 524288;
  ushort* khi   = qlo + 524288;
  ushort* klo   = khi + 524288;
  ushort* wqthi = klo + 524288;              // 2 MB each
  ushort* wqtlo = wqthi + 1048576;
  ushort* wkthi = wqtlo + 1048576;
  ushort* wktlo = wkthi + 1048576;
  float*  GQ    = (float*)(wktlo + 1048576); // [512][1024] f32 (2 MB)
  float*  GKT   = GQ + 524288;               // [1024][512] f32 (2 MB)

  prep<<<dim3(1536), 256, 0, stream>>>(query, keys, Wq, Wk,
                                       qhi, qlo, khi, klo,
                                       wqthi, wqtlo, wkthi, wktlo);
  gemm_mfma<<<dim3(128, 2), 256, 0, stream>>>(qhi, qlo, khi, klo,
                                              wqthi, wqtlo, wkthi, wktlo, GQ, GKT);
  attn_fused<<<dim3(512), 256, 0, stream>>>(GQ, GKT, Va, mask, values, weights, ctx);
}

// Round 14
// 66.277 us; speedup vs baseline: 1.3013x; 1.0132x over previous
//
#include <hip/hip_runtime.h>
#include <hip/hip_bf16.h>

// MultiHeadAttention (additive/Bahdanau): B=2, Q=K=256, HIDDEN=1024, 8 heads x 128
// Pipeline:
//  1) prep:      split query/keys -> bf16 hi/lo; W^T*2log2e -> bf16 hi/lo (LDS transpose)
//  2) gemm_mfma: 3-term bf16 MFMA GEMMs; epilogue stores g = 2^(a/8) (f32 planes):
//                GQ [512][1024], GKT [1024][512]. |a| <= ~500 << 1016 -> g always finite
//                (R12's 2^(a/2) overflowed f32 at |a|>254 -> NaN/clamp-cancellation bug).
//  3) attn_fused (512 blocks x 512 thr): u = gq*gk = 2^((aq+ak)/8) EXACT (combined before
//     any clamp); t = e^{2x} = u^8 via 3 squarings after u<=13 clamp (13^32 < f32max keeps
//     quad denominator finite; clamp active only where tanh = 1-2.4e-9).
//     4-way paired reciprocal: sum va_i/(1+t_i) over d-quad = N/D, one rcp per 4 elems.
//     Waves split d (halves) x k (quarters); d-partials combined in LDS; softmax waves 0-3;
//     PV row-pairs x k-halves over all 8 waves. [~8.5 VALU + 0.25 trans per element]
// Cost model (fitted R5-R11): cyc/wave-elem ~ 4.25*nVALU + 24.5*nTRANS -> ~42 here.

#define TANH_SCALE 2.88539008177792681472f   // 2*log2(e)
#define LOG2E      1.44269504088896340736f
#define UCLAMP     13.0f                     // t = u^8 <= 8.2e8; quad den <= 4.5e35 < f32max

typedef __attribute__((ext_vector_type(8))) short bf16x8_t;   // 8 bf16 = 4 VGPRs
typedef __attribute__((ext_vector_type(4))) float f32x4_t;

__device__ inline ushort bf16_rne(float f) {
  unsigned u = __float_as_uint(f);
  u += 0x7FFFu + ((u >> 16) & 1u);
  return (ushort)(u >> 16);
}
__device__ inline float bf16_to_f(ushort h) { return __uint_as_float((unsigned)h << 16); }
__device__ inline void split1(float v, ushort& hi, ushort& lo) {
  hi = bf16_rne(v);
  lo = bf16_rne(v - bf16_to_f(hi));
}
__device__ inline float pow8c(float u) {     // clamped u^8: 4 VALU
  u = fminf(u, UCLAMP);
  float u2 = u * u;
  float u4 = u2 * u2;
  return u4 * u4;
}

// ---------------- Kernel 1: prep (unchanged) ----------------
__global__ __launch_bounds__(256) void prep(
    const float* __restrict__ query, const float* __restrict__ keys,
    const float* __restrict__ Wq, const float* __restrict__ Wk,
    ushort* __restrict__ qhi, ushort* __restrict__ qlo,
    ushort* __restrict__ khi, ushort* __restrict__ klo,
    ushort* __restrict__ wqthi, ushort* __restrict__ wqtlo,
    ushort* __restrict__ wkthi, ushort* __restrict__ wktlo)
{
  __shared__ float t[64][65];
  const int bid = blockIdx.x, tid = threadIdx.x;
  if (bid < 1024) {
    const int z = bid >> 9;
    const float* in = z ? keys : query;
    ushort* hi = z ? khi : qhi;
    ushort* lo = z ? klo : qlo;
    const size_t i = ((size_t)(bid & 511) * 256 + tid) * 4;
    float4 v = *(const float4*)(in + i);
    ushort h0, h1, h2, h3, l0, l1, l2, l3;
    split1(v.x, h0, l0); split1(v.y, h1, l1);
    split1(v.z, h2, l2); split1(v.w, h3, l3);
    *(ushort4*)(hi + i) = make_ushort4(h0, h1, h2, h3);
    *(ushort4*)(lo + i) = make_ushort4(l0, l1, l2, l3);
  } else {
    const int idx = bid - 1024;
    const int z = idx >> 8;
    const float* W = z ? Wk : Wq;
    ushort* thi = z ? wkthi : wqthi;
    ushort* tlo = z ? wktlo : wqtlo;
    const int n0 = (idx & 15) * 64, h0 = ((idx >> 4) & 15) * 64;
    const int r = tid >> 4, c = (tid & 15) * 4;
#pragma unroll
    for (int i = 0; i < 4; ++i) {
      const int rr = r + i * 16;
      float4 wv = *(const float4*)(W + (size_t)(h0 + rr) * 1024 + n0 + c);
      t[rr][c + 0] = wv.x; t[rr][c + 1] = wv.y;
      t[rr][c + 2] = wv.z; t[rr][c + 3] = wv.w;
    }
    __syncthreads();
#pragma unroll
    for (int i = 0; i < 4; ++i) {
      const int rr = r + i * 16;
      ushort h0v, h1v, h2v, h3v, l0v, l1v, l2v, l3v;
      split1(t[c + 0][rr] * TANH_SCALE, h0v, l0v);
      split1(t[c + 1][rr] * TANH_SCALE, h1v, l1v);
      split1(t[c + 2][rr] * TANH_SCALE, h2v, l2v);
      split1(t[c + 3][rr] * TANH_SCALE, h3v, l3v);
      *(ushort4*)(thi + (size_t)(n0 + rr) * 1024 + h0 + c) = make_ushort4(h0v, h1v, h2v, h3v);
      *(ushort4*)(tlo + (size_t)(n0 + rr) * 1024 + h0 + c) = make_ushort4(l0v, l1v, l2v, l3v);
    }
  }
}

// ---------------- Kernel 2: MFMA GEMM, 3-term bf16 split; g = 2^(a/8) epilogue ----------------
__global__ __launch_bounds__(256) void gemm_mfma(
    const ushort* __restrict__ qhi, const ushort* __restrict__ qlo,
    const ushort* __restrict__ khi, const ushort* __restrict__ klo,
    const ushort* __restrict__ wqthi, const ushort* __restrict__ wqtlo,
    const ushort* __restrict__ wkthi, const ushort* __restrict__ wktlo,
    float* __restrict__ GQ, float* __restrict__ GKT)
{
  const int z = blockIdx.y;
  const int bid = blockIdx.x;
  int m0, n0, ldc;
  const ushort *Ah_g, *Al_g, *Bh_g, *Bl_g;
  float* Gp;
  if (z == 0) {             // GQ [512][1024]
    m0 = (bid >> 4) * 64; n0 = (bid & 15) * 64; ldc = 1024;
    Ah_g = qhi; Al_g = qlo; Bh_g = wqthi; Bl_g = wqtlo; Gp = GQ;
  } else {                  // GKT [1024][512]
    m0 = (bid >> 3) * 64; n0 = (bid & 7) * 64; ldc = 512;
    Ah_g = wkthi; Al_g = wktlo; Bh_g = khi; Bl_g = klo; Gp = GKT;
  }

  __shared__ __align__(16) ushort Ah[64 * 40];
  __shared__ __align__(16) ushort Al[64 * 40];
  __shared__ __align__(16) ushort Bh[64 * 40];
  __shared__ __align__(16) ushort Bl[64 * 40];

  const int tid = threadIdx.x;
  const int srow = tid >> 2, skc = (tid & 3) * 8;
  const size_t gA = (size_t)(m0 + srow) * 1024 + skc;
  const size_t gB = (size_t)(n0 + srow) * 1024 + skc;
  const int soff = srow * 40 + skc;

  uint4 rah = *(const uint4*)(Ah_g + gA);
  uint4 ral = *(const uint4*)(Al_g + gA);
  uint4 rbh = *(const uint4*)(Bh_g + gB);
  uint4 rbl = *(const uint4*)(Bl_g + gB);

  const int w = __builtin_amdgcn_readfirstlane(tid >> 6);
  const int lane = tid & 63;
  const int wm = (w >> 1) * 32, wn = (w & 1) * 32;
  const int fr = lane & 15, kg = lane >> 4;
  const int aoff = (wm + fr) * 40 + kg * 8;
  const int boff = (wn + fr) * 40 + kg * 8;

  f32x4_t acc[2][2] = {};

  for (int kk = 0; kk < 1024; kk += 32) {
    __syncthreads();
    *(uint4*)(Ah + soff) = rah;
    *(uint4*)(Al + soff) = ral;
    *(uint4*)(Bh + soff) = rbh;
    *(uint4*)(Bl + soff) = rbl;
    __syncthreads();

    if (kk + 32 < 1024) {
      rah = *(const uint4*)(Ah_g + gA + kk + 32);
      ral = *(const uint4*)(Al_g + gA + kk + 32);
      rbh = *(const uint4*)(Bh_g + gB + kk + 32);
      rbl = *(const uint4*)(Bl_g + gB + kk + 32);
    }

    bf16x8_t ah0 = *(const bf16x8_t*)(Ah + aoff);
    bf16x8_t ah1 = *(const bf16x8_t*)(Ah + aoff + 16 * 40);
    bf16x8_t al0 = *(const bf16x8_t*)(Al + aoff);
    bf16x8_t al1 = *(const bf16x8_t*)(Al + aoff + 16 * 40);
    bf16x8_t bh0 = *(const bf16x8_t*)(Bh + boff);
    bf16x8_t bh1 = *(const bf16x8_t*)(Bh + boff + 16 * 40);
    bf16x8_t bl0 = *(const bf16x8_t*)(Bl + boff);
    bf16x8_t bl1 = *(const bf16x8_t*)(Bl + boff + 16 * 40);

    acc[0][0] = __builtin_amdgcn_mfma_f32_16x16x32_bf16(ah0, bh0, acc[0][0], 0, 0, 0);
    acc[0][1] = __builtin_amdgcn_mfma_f32_16x16x32_bf16(ah0, bh1, acc[0][1], 0, 0, 0);
    acc[1][0] = __builtin_amdgcn_mfma_f32_16x16x32_bf16(ah1, bh0, acc[1][0], 0, 0, 0);
    acc[1][1] = __builtin_amdgcn_mfma_f32_16x16x32_bf16(ah1, bh1, acc[1][1], 0, 0, 0);
    acc[0][0] = __builtin_amdgcn_mfma_f32_16x16x32_bf16(ah0, bl0, acc[0][0], 0, 0, 0);
    acc[0][1] = __builtin_amdgcn_mfma_f32_16x16x32_bf16(ah0, bl1, acc[0][1], 0, 0, 0);
    acc[1][0] = __builtin_amdgcn_mfma_f32_16x16x32_bf16(ah1, bl0, acc[1][0], 0, 0, 0);
    acc[1][1] = __builtin_amdgcn_mfma_f32_16x16x32_bf16(ah1, bl1, acc[1][1], 0, 0, 0);
    acc[0][0] = __builtin_amdgcn_mfma_f32_16x16x32_bf16(al0, bh0, acc[0][0], 0, 0, 0);
    acc[0][1] = __builtin_amdgcn_mfma_f32_16x16x32_bf16(al0, bh1, acc[0][1], 0, 0, 0);
    acc[1][0] = __builtin_amdgcn_mfma_f32_16x16x32_bf16(al1, bh0, acc[1][0], 0, 0, 0);
    acc[1][1] = __builtin_amdgcn_mfma_f32_16x16x32_bf16(al1, bh1, acc[1][1], 0, 0, 0);
  }

#pragma unroll
  for (int fm = 0; fm < 2; ++fm)
#pragma unroll
    for (int fn = 0; fn < 2; ++fn) {
      const int col = n0 + wn + fn * 16 + fr;
#pragma unroll
      for (int j = 0; j < 4; ++j) {
        const int row = m0 + wm + fm * 16 + kg * 4 + j;
        Gp[(size_t)row * ldc + col] = __builtin_amdgcn_exp2f(acc[fm][fn][j] * 0.125f);
      }
    }
}

// ---------------- Kernel 3: fused attn, 8 waves, d-split + 4-way paired rcp ----------------
// grid 512 x 512 thr: block = (b,h) = bid>>5, q-tile = (bid&31)*8.
// Wave w: d-half dh = w>>2, k-quarter kq = w&3, lane k = kq*64+lane.
__global__ __launch_bounds__(512) void attn_fused(
    const float* __restrict__ GQ, const float* __restrict__ GKT,
    const float* __restrict__ Va, const int* __restrict__ mask,
    const float* __restrict__ values,
    float* __restrict__ weights, float* __restrict__ ctx)
{
  __shared__ __align__(16) float gq_s[8][128];
  __shared__ __align__(16) float va_s[128];
  __shared__ __align__(16) float acc_lds[4][64][8];
  __shared__ float red_m[4][8];
  __shared__ float red_s[4][8];
  __shared__ __align__(16) float P_lds[8][256];
  __shared__ __align__(16) float4 pv_part[4][2][32];

  const int tid = threadIdx.x;
  const int lane = tid & 63;
  const int w = __builtin_amdgcn_readfirstlane(tid >> 6);
  const int bid = blockIdx.x;
  const int bh = bid >> 5;
  const int b = bh & 1, h = bh >> 1;
  const int qt = (bid & 31) * 8;
  const int dh = w >> 2, kq = w & 3;
  const int k = kq * 64 + lane;

  // stage gq tile (8x128) + Va head slice into LDS
  {
    const int i2 = tid * 2;
    const int sq = i2 >> 7, sd = i2 & 127;
    *(float2*)&gq_s[sq][sd] =
        *(const float2*)(GQ + (size_t)(b * 256 + qt + sq) * 1024 + h * 128 + sd);
    if (tid < 32) *(float4*)&va_s[tid * 4] = *(const float4*)(Va + h * 128 + tid * 4);
  }

  const float pen = 99.0f * (1.0f - (float)mask[b * 256 + k]);

  float ssum = Va[h * 128 + lane] + Va[h * 128 + 64 + lane];
#pragma unroll
  for (int off = 32; off; off >>= 1) ssum += __shfl_xor(ssum, off, 64);

  const float* gkp = GKT + (size_t)(h * 128 + dh * 64) * 512 + b * 256 + k;  // + d*512

  __syncthreads();

  float acc[8] = {0.f, 0.f, 0.f, 0.f, 0.f, 0.f, 0.f, 0.f};

  float gkc[8];
#pragma unroll
  for (int j = 0; j < 8; ++j) gkc[j] = gkp[(size_t)j * 512];

  for (int ch = 0; ch < 8; ++ch) {      // 8 chunks x 8 d = 64 d per wave
    const int d0 = ch * 8;
    float gkn[8];
    if (ch < 7) {
#pragma unroll
      for (int j = 0; j < 8; ++j) gkn[j] = gkp[(size_t)(d0 + 8 + j) * 512];
    }
    float va_[8];
    *(float4*)&va_[0] = *(const float4*)&va_s[dh * 64 + d0];
    *(float4*)&va_[4] = *(const float4*)&va_s[dh * 64 + d0 + 4];
    const float s01 = va_[0] + va_[1], s23 = va_[2] + va_[3];
    const float s45 = va_[4] + va_[5], s67 = va_[6] + va_[7];
#pragma unroll
    for (int q = 0; q < 8; ++q) {
      float gqr[8];
      *(float4*)&gqr[0] = *(const float4*)&gq_s[q][dh * 64 + d0];      // broadcast reads
      *(float4*)&gqr[4] = *(const float4*)&gq_s[q][dh * 64 + d0 + 4];
      // quad A: d0..d3
      {
        const float t0 = pow8c(gqr[0] * gkc[0]);
        const float t1 = pow8c(gqr[1] * gkc[1]);
        const float t2 = pow8c(gqr[2] * gkc[2]);
        const float t3 = pow8c(gqr[3] * gkc[3]);
        const float p01 = fmaf(t0, t1, t0 + t1 + 1.0f);
        const float p23 = fmaf(t2, t3, t2 + t3 + 1.0f);
        const float den = p01 * p23;
        const float n01 = fmaf(va_[0], t1, fmaf(va_[1], t0, s01));
        const float n23 = fmaf(va_[2], t3, fmaf(va_[3], t2, s23));
        const float N = fmaf(n01, p23, n23 * p01);
        acc[q] = fmaf(N, __builtin_amdgcn_rcpf(den), acc[q]);
      }
      // quad B: d4..d7
      {
        const float t0 = pow8c(gqr[4] * gkc[4]);
        const float t1 = pow8c(gqr[5] * gkc[5]);
        const float t2 = pow8c(gqr[6] * gkc[6]);
        const float t3 = pow8c(gqr[7] * gkc[7]);
        const float p01 = fmaf(t0, t1, t0 + t1 + 1.0f);
        const float p23 = fmaf(t2, t3, t2 + t3 + 1.0f);
        const float den = p01 * p23;
        const float n01 = fmaf(va_[4], t1, fmaf(va_[5], t0, s45));
        const float n23 = fmaf(va_[6], t3, fmaf(va_[7], t2, s67));
        const float N = fmaf(n01, p23, n23 * p01);
        acc[q] = fmaf(N, __builtin_amdgcn_rcpf(den), acc[q]);
      }
    }
    if (ch < 7) {
#pragma unroll
      for (int j = 0; j < 8; ++j) gkc[j] = gkn[j];
    }
  }

  // combine d-halves: waves 4-7 export, waves 0-3 absorb
  if (w >= 4) {
#pragma unroll
    for (int q = 0; q < 8; ++q) acc_lds[kq][lane][q] = acc[q];
  }
  __syncthreads();

  float l[8], p[8];
  if (w < 4) {
#pragma unroll
    for (int q = 0; q < 8; ++q) {
      acc[q] += acc_lds[kq][lane][q];
      l[q] = ssum - 2.0f * acc[q] - pen;
    }
#pragma unroll
    for (int q = 0; q < 8; ++q) {
      float m = l[q];
#pragma unroll
      for (int off = 32; off; off >>= 1) m = fmaxf(m, __shfl_xor(m, off, 64));
      if (lane == 0) red_m[w][q] = m;
    }
  }
  __syncthreads();
  if (w < 4) {
#pragma unroll
    for (int q = 0; q < 8; ++q) {
      float m = fmaxf(fmaxf(red_m[0][q], red_m[1][q]), fmaxf(red_m[2][q], red_m[3][q]));
      p[q] = __builtin_amdgcn_exp2f((l[q] - m) * LOG2E);
    }
#pragma unroll
    for (int q = 0; q < 8; ++q) {
      float s = p[q];
#pragma unroll
      for (int off = 32; off; off >>= 1) s += __shfl_xor(s, off, 64);
      if (lane == 0) red_s[w][q] = s;
    }
  }
  __syncthreads();
  if (w < 4) {
#pragma unroll
    for (int q = 0; q < 8; ++q) {
      const float s = (red_s[0][q] + red_s[1][q]) + (red_s[2][q] + red_s[3][q]);
      const float pq = p[q] / s;
      weights[((size_t)((b * 8 + h) * 256) + qt + q) * 256 + k] = pq;
      P_lds[q][k] = pq;
    }
  }
  __syncthreads();

  // PV: wave w -> row pair rp = w&3 (rows 2rp, 2rp+1), k-half kh = w>>2.
  {
    const int rp = w & 3, kh = w >> 2;
    const int d4 = lane & 31, ks = lane >> 5;
    const int q0 = rp * 2, q1 = q0 + 1;
    const float* vb = values + (size_t)(b * 256 + kh * 128 + ks * 64) * 1024 + h * 128 + d4 * 4;
    const float* w0p = &P_lds[q0][kh * 128 + ks * 64];
    const float* w1p = &P_lds[q1][kh * 128 + ks * 64];
    float4 A0 = make_float4(0, 0, 0, 0), A1 = make_float4(0, 0, 0, 0);
#pragma unroll 4
    for (int j = 0; j < 64; ++j) {
      float4 v = *(const float4*)(vb + (size_t)j * 1024);
      const float pw0 = w0p[j], pw1 = w1p[j];
      A0.x += pw0 * v.x; A0.y += pw0 * v.y; A0.z += pw0 * v.z; A0.w += pw0 * v.w;
      A1.x += pw1 * v.x; A1.y += pw1 * v.y; A1.z += pw1 * v.z; A1.w += pw1 * v.w;
    }
    A0.x += __shfl_xor(A0.x, 32, 64); A0.y += __shfl_xor(A0.y, 32, 64);
    A0.z += __shfl_xor(A0.z, 32, 64); A0.w += __shfl_xor(A0.w, 32, 64);
    A1.x += __shfl_xor(A1.x, 32, 64); A1.y += __shfl_xor(A1.y, 32, 64);
    A1.z += __shfl_xor(A1.z, 32, 64); A1.w += __shfl_xor(A1.w, 32, 64);
    if (w >= 4 && lane < 32) {
      pv_part[rp][0][d4] = A0;
      pv_part[rp][1][d4] = A1;
    }
    __syncthreads();
    if (w < 4 && lane < 32) {
      float4 pa = pv_part[rp][0][d4];
      float4 pb = pv_part[rp][1][d4];
      A0.x += pa.x; A0.y += pa.y; A0.z += pa.z; A0.w += pa.w;
      A1.x += pb.x; A1.y += pb.y; A1.z += pb.z; A1.w += pb.w;
      *(float4*)&ctx[(size_t)(b * 256 + qt + q0) * 1024 + h * 128 + d4 * 4] = A0;
      *(float4*)&ctx[(size_t)(b * 256 + qt + q1) * 1024 + h * 128 + d4 * 4] = A1;
    }
  }
}

extern "C" void kernel_launch(void* const* d_in, const int* in_sizes, int n_in,
                              void* d_out, int out_size, void* d_ws, size_t ws_size,
                              hipStream_t stream) {
  const float* query  = (const float*)d_in[0];
  const float* keys   = (const float*)d_in[1];
  const float* values = (const float*)d_in[2];
  const int*   mask   = (const int*)d_in[3];
  const float* Wq     = (const float*)d_in[4];
  const float* Wk     = (const float*)d_in[5];
  const float* Va     = (const float*)d_in[6];

  float* ctx     = (float*)d_out;            // [2,256,1024]
  float* weights = ctx + 524288;             // [2,8,256,256]

  // ws layout (~16 MB used):
  ushort* qhi   = (ushort*)d_ws;             // 1 MB each
  ushort* qlo   = qhi + 524288;
  ushort* khi   = qlo + 524288;
  ushort* klo   = khi + 524288;
  ushort* wqthi = klo + 524288;              // 2 MB each
  ushort* wqtlo = wqthi + 1048576;
  ushort* wkthi = wqtlo + 1048576;
  ushort* wktlo = wkthi + 1048576;
  float*  GQ    = (float*)(wktlo + 1048576); // [512][1024] f32 (2 MB)
  float*  GKT   = GQ + 524288;               // [1024][512] f32 (2 MB)

  prep<<<dim3(1536), 256, 0, stream>>>(query, keys, Wq, Wk,
                                       qhi, qlo, khi, klo,
                                       wqthi, wqtlo, wkthi, wktlo);
  gemm_mfma<<<dim3(128, 2), 256, 0, stream>>>(qhi, qlo, khi, klo,
                                              wqthi, wqtlo, wkthi, wktlo, GQ, GKT);
  attn_fused<<<dim3(512), 512, 0, stream>>>(GQ, GKT, Va, mask, values, weights, ctx);
}